// Round 4
// baseline (128.225 us; speedup 1.0000x reference)
//
#include <hip/hip_runtime.h>

#define Bn 256
#define Tn 256
#define Hn 16
#define Dn 88
#define LOG16 2.7725887222397811f

// ---------------------------------------------------------------------------
// DPP helpers: row_ror rotations within 16-lane rows; self-calibrated usage.
// ---------------------------------------------------------------------------
template<int CTRL>
__device__ __forceinline__ float dppf(float x) {
    return __int_as_float(__builtin_amdgcn_update_dpp(
        0, __float_as_int(x), CTRL, 0xF, 0xF, true));
}
#define GATHER16(dst, s)                                                     \
    dst[0] = (s);                                                            \
    dst[1] = dppf<0x128>(dst[0]);                                            \
    dst[2] = dppf<0x124>(dst[0]); dst[3]  = dppf<0x124>(dst[1]);             \
    dst[4] = dppf<0x122>(dst[0]); dst[5]  = dppf<0x122>(dst[1]);             \
    dst[6] = dppf<0x122>(dst[2]); dst[7]  = dppf<0x122>(dst[3]);             \
    dst[8] = dppf<0x121>(dst[0]); dst[9]  = dppf<0x121>(dst[1]);             \
    dst[10] = dppf<0x121>(dst[2]); dst[11] = dppf<0x121>(dst[3]);            \
    dst[12] = dppf<0x121>(dst[4]); dst[13] = dppf<0x121>(dst[5]);            \
    dst[14] = dppf<0x121>(dst[6]); dst[15] = dppf<0x121>(dst[7]);

__device__ __forceinline__ float rowsum16(float v) {
    v += dppf<0x128>(v); v += dppf<0x124>(v);
    v += dppf<0x122>(v); v += dppf<0x121>(v);
    return v;
}

// pack the 4 nibbles of a word (bits 0-3 of each byte) into low 16 bits
__device__ __forceinline__ unsigned compress4(unsigned w) {
    unsigned y = (w | (w >> 4)) & 0x00FF00FFu;
    return (y | (y >> 8)) & 0xFFFFu;
}

// ---------------------------------------------------------------------------
// One block per sequence b. 256 threads.
// Load schedule maximizes memory-level parallelism:
//   (1) issue 3 coalesced float4 loads of probs_y
//   (2) issue ALL 22 float4 loads of seq[b] (22 outstanding vmem/wave)
//   (3) compute LUT logs (waits only on probs_y; seq still in flight)
//   (4) nibble-pack seq into 6KB LDS
//   (5) emissions -> Esh/Msh in LDS
//   (6) wave 0: DPP-gather scaled linear-space forward recursion
// ---------------------------------------------------------------------------
__global__ __launch_bounds__(256, 1) void fused_kernel(
    const float* __restrict__ seq,
    const int*   __restrict__ lengths,
    const float* __restrict__ probs_x,
    const float* __restrict__ probs_y,
    float* __restrict__ out)
{
    __shared__ __align__(16) float lut[Dn * 64];   // 22528 B  [d][pc][h]
    __shared__ unsigned nibW[Tn * 6];              //  6144 B  4 bits/elem
    __shared__ __align__(16) float Esh[Tn * Hn];   // 16384 B
    __shared__ float Msh[Tn];                      //  1024 B

    const int tid = threadIdx.x;
    const int b = blockIdx.x;
    const float4* seqv = (const float4*)(seq + (size_t)b * Tn * Dn);
    const float4* pyv  = (const float4*)probs_y;   // 704 float4

    // ---- (1) probs_y loads first (small, coalesced) ----
    float4 py[3];
    #pragma unroll
    for (int k = 0; k < 3; ++k) {
        int i = tid + (k << 8);
        py[k] = (i < 704) ? pyv[i] : make_float4(0.5f, 0.5f, 0.5f, 0.5f);
    }

    // ---- (2) batch-issue ALL seq loads (MLP: 22 dwordx4 in flight) ----
    float4 vbuf[22];
    #pragma unroll
    for (int k = 0; k < 22; ++k) vbuf[k] = seqv[tid + (k << 8)];

    // ---- (3) LUT while seq loads are in flight ----
    #pragma unroll
    for (int k = 0; k < 3; ++k) {
        int i = tid + (k << 8);
        if (i < 704) {
            int h = i / 44;               // 44 float4 per h
            int rem = i - h * 44;
            int prev = rem / 22;
            int jj = rem - prev * 22;
            int d = jj << 2;
            float pv[4] = {py[k].x, py[k].y, py[k].z, py[k].w};
            #pragma unroll
            for (int m = 0; m < 4; ++m) {
                lut[(d + m) * 64 + (prev * 2 + 1) * 16 + h] = __logf(pv[m]);
                lut[(d + m) * 64 + (prev * 2) * 16 + h]     = __logf(1.0f - pv[m]);
            }
        }
    }

    // ---- (4) nibble pack ----
    ((unsigned short*)nibW)[tid * 12 + 11] = 0;        // zero pad bytes 22..23
    #pragma unroll
    for (int k = 0; k < 22; ++k) {
        int f = tid + (k << 8);                        // flat float4 index
        int t = f / 22, jj = f - t * 22;
        float4 v = vbuf[k];
        unsigned nib = (v.x > 0.5f ? 1u : 0u) | (v.y > 0.5f ? 2u : 0u) |
                       (v.z > 0.5f ? 4u : 0u) | (v.w > 0.5f ? 8u : 0u);
        ((unsigned char*)nibW)[t * 24 + jj] = (unsigned char)nib;
    }
    __syncthreads();

    // ---- (5) emissions into LDS ----
    const float4* lv = (const float4*)lut;
    #pragma unroll
    for (int r = 0; r < 4; ++r) {
        int task = (r << 8) + tid;
        int t = task >> 2, h4i = task & 3;
        unsigned cw0, cw1, cw2, pw0, pw1, pw2;
        {
            unsigned c0 = compress4(nibW[t * 6 + 0]), c1 = compress4(nibW[t * 6 + 1]);
            unsigned c2 = compress4(nibW[t * 6 + 2]), c3 = compress4(nibW[t * 6 + 3]);
            unsigned c4 = compress4(nibW[t * 6 + 4]), c5 = compress4(nibW[t * 6 + 5]);
            cw0 = c0 | (c1 << 16); cw1 = c2 | (c3 << 16); cw2 = c4 | (c5 << 16);
        }
        if (t > 0) {
            unsigned c0 = compress4(nibW[t * 6 - 6]), c1 = compress4(nibW[t * 6 - 5]);
            unsigned c2 = compress4(nibW[t * 6 - 4]), c3 = compress4(nibW[t * 6 - 3]);
            unsigned c4 = compress4(nibW[t * 6 - 2]), c5 = compress4(nibW[t * 6 - 1]);
            pw0 = c0 | (c1 << 16); pw1 = c2 | (c3 << 16); pw2 = c4 | (c5 << 16);
        } else { pw0 = pw1 = pw2 = 0; }

        float4 acc = {0.f, 0.f, 0.f, 0.f};
        #pragma unroll 8
        for (int d = 0; d < 32; ++d) {
            int idx = (d << 4) + (((pw0 >> d) & 1u) << 3) + (((cw0 >> d) & 1u) << 2) + h4i;
            float4 v = lv[idx];
            acc.x += v.x; acc.y += v.y; acc.z += v.z; acc.w += v.w;
        }
        #pragma unroll 8
        for (int d = 0; d < 32; ++d) {
            int idx = ((d + 32) << 4) + (((pw1 >> d) & 1u) << 3) + (((cw1 >> d) & 1u) << 2) + h4i;
            float4 v = lv[idx];
            acc.x += v.x; acc.y += v.y; acc.z += v.z; acc.w += v.w;
        }
        #pragma unroll 8
        for (int d = 0; d < 24; ++d) {
            int idx = ((d + 64) << 4) + (((pw2 >> d) & 1u) << 3) + (((cw2 >> d) & 1u) << 2) + h4i;
            float4 v = lv[idx];
            acc.x += v.x; acc.y += v.y; acc.z += v.z; acc.w += v.w;
        }

        float mx = fmaxf(fmaxf(acc.x, acc.y), fmaxf(acc.z, acc.w));
        mx = fmaxf(mx, __shfl_xor(mx, 1, 4));
        mx = fmaxf(mx, __shfl_xor(mx, 2, 4));
        float4 E;
        E.x = __expf(acc.x - mx); E.y = __expf(acc.y - mx);
        E.z = __expf(acc.z - mx); E.w = __expf(acc.w - mx);
        ((float4*)Esh)[(t << 2) + h4i] = E;
        if (h4i == 0) Msh[t] = mx;
    }
    __syncthreads();

    // ---- (6) forward recursion, wave 0 only ----
    if (tid >= 64) return;
    const int j = tid & 15;
    int len = lengths[b];
    len = min(max(len, 0), Tn);

    float cal[16];
    GATHER16(cal, (float)j);                    // learn the network's permutation
    float pcr[16];
    #pragma unroll
    for (int k = 0; k < 16; ++k) pcr[k] = probs_x[((int)cal[k]) * Hn + j];

    float msum = 0.0f;
    #pragma unroll
    for (int k = 0; k < 16; ++k) {
        int t = j + (k << 4);
        float m = Msh[t];
        msum += (t < len) ? m : 0.0f;
    }
    float L = rowsum16(msum);

    float a = (j == 0) ? 1.0f : 0.0f;
    float eb[8];
    #pragma unroll
    for (int k = 0; k < 8; ++k) eb[k] = Esh[(k << 4) + j];

    #pragma unroll 8
    for (int t = 0; t < len; ++t) {
        float e = eb[t & 7];
        int tn = t + 8; tn = (tn < Tn) ? tn : (Tn - 1);
        eb[t & 7] = Esh[(tn << 4) + j];

        float y[16];
        GATHER16(y, a);
        float s0 = y[0] * pcr[0], s1 = y[1] * pcr[1];
        float s2 = y[2] * pcr[2], s3 = y[3] * pcr[3];
        #pragma unroll
        for (int k = 4; k < 16; k += 4) {
            s0 = fmaf(y[k + 0], pcr[k + 0], s0);
            s1 = fmaf(y[k + 1], pcr[k + 1], s1);
            s2 = fmaf(y[k + 2], pcr[k + 2], s2);
            s3 = fmaf(y[k + 3], pcr[k + 3], s3);
        }
        a = ((s0 + s1) + (s2 + s3)) * e;

        if ((t & 7) == 7) {                     // renorm (identity on L+log S)
            float S = rowsum16(a);
            a *= (1.0f / S);
            L += __logf(S);
        }
    }

    float S = rowsum16(a);
    float res = L + __logf(S) + (float)(Tn - len) * LOG16;
    if (tid == 0) atomicAdd(out, res);
}

extern "C" void kernel_launch(void* const* d_in, const int* in_sizes, int n_in,
                              void* d_out, int out_size, void* d_ws, size_t ws_size,
                              hipStream_t stream) {
    const float* seq     = (const float*)d_in[0];
    const int*   lengths = (const int*)  d_in[1];
    const float* probs_x = (const float*)d_in[2];
    const float* probs_y = (const float*)d_in[3];
    float* out = (float*)d_out;

    hipMemsetAsync(d_out, 0, sizeof(float) * out_size, stream);
    fused_kernel<<<Bn, 256, 0, stream>>>(seq, lengths, probs_x, probs_y, out);
}